// Round 2
// baseline (10099.602 us; speedup 1.0000x reference)
//
#include <hip/hip_runtime.h>
#include <stdint.h>
#include <stddef.h>

#define TT   128
#define BB   1024
#define INN  75
#define HH   128
#define KXP  96
#define OUTN 256
#define DECN 9600
#define EPSB 1e-5f
#define NRB  64

typedef short v8s __attribute__((ext_vector_type(8)));   // 8 bf16 (4 VGPR) MFMA frag
typedef float v4f __attribute__((ext_vector_type(4)));   // 4 fp32 acc frag
typedef unsigned short ush;
typedef unsigned int   u32;
typedef unsigned long long u64;

// ---- static device workspace (fully rewritten every launch) ----
__device__ __align__(256) ush g_xpad[(size_t)TT * BB * KXP];   // x padded to K=96, [t][b][k] bf16
__device__ __align__(256) u64 g_G1[(size_t)TT * 32 * BB * 4];  // BN(x@Wih0)+b0, [t][g][row][16 bf16]
__device__ __align__(256) u64 g_h0s[(size_t)TT * BB * 32];     // h0 stream [t][row][128 bf16] as u64
__device__ __align__(256) u64 g_h1s[(size_t)BB * 32];          // h1 final step only
// weights [m][k] bf16, m permuted: origcol(m) = (m&3)*128 + (m>>4)*4 + ((m>>2)&3)
__device__ __align__(256) ush g_wtih0[512 * KXP];
__device__ __align__(256) ush g_wthh0[512 * HH];
__device__ __align__(256) ush g_wtih1[512 * HH];
__device__ __align__(256) ush g_wthh1[512 * HH];
__device__ __align__(256) ush g_fcwt[OUTN * HH];               // fc_w^T [col][k]
__device__ __align__(256) ush g_decwt[(size_t)DECN * OUTN];    // dec_w^T [col][k]
__device__ __align__(256) ush g_emb[BB * OUTN];                // fc output bf16

// ---- sync state (all monotone counters; every flag += fixed count per launch) ----
__device__ u32 g_F1[2][NRB];        // gate-partials-in-accumulator, per (layer, row-block)
__device__ u32 g_F3[2][NRB];        // c-partials-in-accumulator
__device__ u32 g_F5[NRB];           // h0[t] published by L0 row-block
__device__ u32 g_Fend[2 * NRB];     // end-of-launch barrier
// rotating (mod 4) BN stat accumulators; zero at every launch boundary
__device__ __align__(256) float g_acc[3][4][512][2];   // [stream: hh0,ih1,hh1][buf][col][S,Q]
__device__ __align__(256) float g_cacc[2][4][128][2];  // [layer][buf][unit][S,Q]

// ---- helpers ----
__device__ __forceinline__ ush f2bf(float f) {
  u32 u = __float_as_uint(f);
  u32 r = (u + 0x7FFFu + ((u >> 16) & 1u)) >> 16;   // RNE
  return (ush)r;
}
__device__ __forceinline__ float bf2f(ush u) { return __uint_as_float(((u32)u) << 16); }
__device__ __forceinline__ float sigf(float x)  { return 1.f / (1.f + __expf(-x)); }
__device__ __forceinline__ float tanhf_(float x){ float e = __expf(2.f * x); return 1.f - 2.f / (e + 1.f); }
__device__ __forceinline__ v8s ld8(const ush* p) { return *reinterpret_cast<const v8s*>(p); }
__device__ __forceinline__ int origcol(int m) { return (m & 3) * 128 + (m >> 4) * 4 + ((m >> 2) & 3); }
// XOR-swizzled byte offset into the [16 rows][256B] own-h LDS tile (kills ds bank conflicts)
__device__ __forceinline__ int hswz(int r, int b) { return (r * 256 + b) ^ ((r & 7) << 4); }

__device__ __forceinline__ u32 aload(const u32* p) {
  return __hip_atomic_load(p, __ATOMIC_RELAXED, __HIP_MEMORY_SCOPE_AGENT);
}
__device__ __forceinline__ void astore(u32* p, u32 v) {
  __hip_atomic_store(p, v, __ATOMIC_RELEASE, __HIP_MEMORY_SCOPE_AGENT);
}
__device__ __forceinline__ void fadd(float* p, float v) {
  __hip_atomic_fetch_add(p, v, __ATOMIC_RELAXED, __HIP_MEMORY_SCOPE_AGENT);
}
__device__ __forceinline__ void fzero(float* p) {
  __hip_atomic_store(p, 0.f, __ATOMIC_RELAXED, __HIP_MEMORY_SCOPE_AGENT);
}

// ---- prep kernels (unchanged) ----
__global__ void kpackx(const float* __restrict__ seq) {
  int idx = blockIdx.x * 256 + threadIdx.x;   // < TT*BB*KXP
  int kk = idx % KXP; int rest = idx / KXP;
  int b = rest % BB;  int t = rest / BB;
  float v = (kk < INN) ? seq[((size_t)b * TT + t) * INN + kk] : 0.f;
  g_xpad[idx] = f2bf(v);
}

__global__ void kpackw(const float* __restrict__ Wih0, const float* __restrict__ Whh0,
                       const float* __restrict__ Wih1, const float* __restrict__ Whh1,
                       const float* __restrict__ fcw,  const float* __restrict__ decw) {
  int idx = blockIdx.x * 256 + threadIdx.x;   // grid 10688
  if (idx < 49152) {                          // wtih0: [m][96]
    int m = idx / KXP, k = idx % KXP;
    g_wtih0[idx] = f2bf((k < INN) ? Wih0[k * 512 + origcol(m)] : 0.f);
  } else if (idx < 114688) {
    int j = idx - 49152; int m = j / HH, k = j % HH;
    g_wthh0[j] = f2bf(Whh0[k * 512 + origcol(m)]);
  } else if (idx < 180224) {
    int j = idx - 114688; int m = j / HH, k = j % HH;
    g_wtih1[j] = f2bf(Wih1[k * 512 + origcol(m)]);
  } else if (idx < 245760) {
    int j = idx - 180224; int m = j / HH, k = j % HH;
    g_wthh1[j] = f2bf(Whh1[k * 512 + origcol(m)]);
  } else if (idx < 278528) {                  // fcwt [c][128]
    int j = idx - 245760; int c = j / HH, k = j % HH;
    g_fcwt[j] = f2bf(fcw[k * OUTN + c]);
  } else {                                    // decwt [c][256], coalesced reads
    int j = idx - 278528; int n = j % DECN, k = j / DECN;
    g_decwt[(size_t)n * OUTN + k] = f2bf(decw[(size_t)k * DECN + n]);
  }
}

// G1[t][g][row][16] = BN_ih0(x_t @ Wih0) + b0 (folded), transposed-MFMA orientation.
__global__ __launch_bounds__(512) void kprep(const float* __restrict__ gih0,
                                             const float* __restrict__ bih0,
                                             const float* __restrict__ b0) {
  const int t = blockIdx.x >> 3, ct = blockIdx.x & 7;
  const int tid = threadIdx.x, wv = tid >> 6, l = tid & 63;
  const int lm = l & 15, lq = l >> 4;
  const int R0 = wv * 128;
  __shared__ float sred[8][64][2];
  __shared__ float scoef[64][2];

  v8s af[4][3];
#pragma unroll
  for (int tt = 0; tt < 4; ++tt)
#pragma unroll
    for (int ks = 0; ks < 3; ++ks)
      af[tt][ks] = ld8(&g_wtih0[(ct * 64 + tt * 16 + lm) * KXP + ks * 32 + lq * 8]);

  const v4f vz = {0.f, 0.f, 0.f, 0.f};
  v4f acc[8][4];
#pragma unroll
  for (int mt = 0; mt < 8; ++mt)
#pragma unroll
    for (int tt = 0; tt < 4; ++tt) acc[mt][tt] = vz;

#pragma unroll
  for (int mt = 0; mt < 8; ++mt) {
    const ush* xr = g_xpad + ((size_t)t * BB + R0 + mt * 16 + lm) * KXP + lq * 8;
    v8s bx0 = ld8(xr), bx1 = ld8(xr + 32), bx2 = ld8(xr + 64);
#pragma unroll
    for (int tt = 0; tt < 4; ++tt) {
      acc[mt][tt] = __builtin_amdgcn_mfma_f32_16x16x32_bf16(af[tt][0], bx0, acc[mt][tt], 0, 0, 0);
      acc[mt][tt] = __builtin_amdgcn_mfma_f32_16x16x32_bf16(af[tt][1], bx1, acc[mt][tt], 0, 0, 0);
      acc[mt][tt] = __builtin_amdgcn_mfma_f32_16x16x32_bf16(af[tt][2], bx2, acc[mt][tt], 0, 0, 0);
    }
  }
  float S[4][4], Q[4][4];
#pragma unroll
  for (int tt = 0; tt < 4; ++tt)
#pragma unroll
    for (int r = 0; r < 4; ++r) {
      float s = 0.f, q = 0.f;
#pragma unroll
      for (int mt = 0; mt < 8; ++mt) { float a = acc[mt][tt][r]; s += a; q += a * a; }
#pragma unroll
      for (int off = 1; off < 16; off <<= 1) { s += __shfl_xor(s, off); q += __shfl_xor(q, off); }
      S[tt][r] = s; Q[tt][r] = q;
    }
  if (lm == 0)
#pragma unroll
    for (int tt = 0; tt < 4; ++tt)
#pragma unroll
      for (int r = 0; r < 4; ++r) {
        sred[wv][tt * 16 + lq * 4 + r][0] = S[tt][r];
        sred[wv][tt * 16 + lq * 4 + r][1] = Q[tt][r];
      }
  __syncthreads();
  if (tid < 64) {
    float Sa = 0.f, Qa = 0.f;
#pragma unroll
    for (int w8 = 0; w8 < 8; ++w8) { Sa += sred[w8][tid][0]; Qa += sred[w8][tid][1]; }
    int oc = origcol(ct * 64 + tid);
    float m_ = Sa * (1.f / BB), v_ = Qa * (1.f / BB) - m_ * m_;
    float A = gih0[oc] * rsqrtf(v_ + EPSB);
    scoef[tid][0] = A; scoef[tid][1] = bih0[oc] - A * m_ + b0[oc];
  }
  __syncthreads();
  float CA[4][4], CD[4][4];
#pragma unroll
  for (int tt = 0; tt < 4; ++tt)
#pragma unroll
    for (int r = 0; r < 4; ++r) {
      CA[tt][r] = scoef[tt * 16 + lq * 4 + r][0];
      CD[tt][r] = scoef[tt * 16 + lq * 4 + r][1];
    }
#pragma unroll
  for (int mt = 0; mt < 8; ++mt) {
    const int row = R0 + mt * 16 + lm;
#pragma unroll
    for (int tt = 0; tt < 4; ++tt) {
      const int g = ct * 4 + tt;
      u32 lo = (u32)f2bf(CA[tt][0] * acc[mt][tt][0] + CD[tt][0])
             | ((u32)f2bf(CA[tt][1] * acc[mt][tt][1] + CD[tt][1]) << 16);
      u32 hi = (u32)f2bf(CA[tt][2] * acc[mt][tt][2] + CD[tt][2])
             | ((u32)f2bf(CA[tt][3] * acc[mt][tt][3] + CD[tt][3]) << 16);
      g_G1[(((size_t)t * 32 + g) * BB + row) * 4 + lq] = (u64)lo | ((u64)hi << 32);
    }
  }
}

// ---- krec2: row-owner persistent recurrence.
// 128 blocks x 512 thr. Block = (L = bid>>6, rb = bid&63 -> rows rb*16..+15).
// Each block computes ALL 512 gate cols for its 16 rows: weights in registers,
// own h via LDS (L0 GEMM input is its own output -> no global h traffic for L0;
// L1 reads h0[rows] p2p from one L0 block). BN stats: per-(col) partials over
// 16 rows -> device-scope fp32 atomicAdd into mod-4 accumulators -> ONE flag
// round per BN (gates, c). L0 never waits on L1 and runs ahead, so L1's F5
// wait is ~free. Lane: row = rb*16+lm, unit = w*16+ct*4+lq, gate = r.
__global__ __launch_bounds__(512, 2) void krec2(
    const float* __restrict__ ghh0, const float* __restrict__ bhh0,
    const float* __restrict__ gc0,  const float* __restrict__ bc0,
    const float* __restrict__ gih1, const float* __restrict__ bih1,
    const float* __restrict__ ghh1, const float* __restrict__ bhh1,
    const float* __restrict__ b1,   const float* __restrict__ gc1,
    const float* __restrict__ bc1) {
  const int bid = blockIdx.x;
  const int L = bid >> 6, rb = bid & 63;
  const int tid = threadIdx.x, w = tid >> 6, l = tid & 63;
  const int lm = l & 15, lq = l >> 4;
  const int row = rb * 16 + lm;

  __shared__ float s_gamA[512], s_gamB[512], s_bsum[512];
  __shared__ float s_cg[128], s_cb[128];
  __shared__ u64 s_h[16 * 32];          // own-h staging [16 rows][256B], XOR-swizzled
  __shared__ u32 s_base[2];

  if (tid == 0) {
    s_base[0] = aload(&g_F1[L][rb]);    // own flags -> race-free epoch base (=128n)
    s_base[1] = aload(&g_Fend[bid]);    // (=n)
  }
  {
    const int m = tid;                  // 512 threads <-> 512 cols
    const int oc = origcol(m);
    if (L == 0) { s_gamA[m] = ghh0[oc]; s_bsum[m] = bhh0[oc]; }
    else { s_gamA[m] = gih1[oc]; s_gamB[m] = ghh1[oc]; s_bsum[m] = bih1[oc] + bhh1[oc] + b1[oc]; }
    if (tid < 128) { s_cg[tid] = (L ? gc1 : gc0)[tid]; s_cb[tid] = (L ? bc1 : bc0)[tid]; }
  }
  __syncthreads();
  const u32 base = s_base[0], baseE = s_base[1];

  // persistent weight fragments: wave w owns cols (w*4+ct)*16..+15, ct=0..3
  v8s afA[4][4], afB[4][4];
  {
    const ush* wA = (L == 0) ? g_wthh0 : g_wtih1;
#pragma unroll
    for (int ct = 0; ct < 4; ++ct)
#pragma unroll
      for (int ks = 0; ks < 4; ++ks) {
        afA[ct][ks] = ld8(&wA[((w * 4 + ct) * 16 + lm) * HH + ks * 32 + lq * 8]);
        if (L == 1) afB[ct][ks] = ld8(&g_wthh1[((w * 4 + ct) * 16 + lm) * HH + ks * 32 + lq * 8]);
      }
  }

  const int stA = (L == 0) ? 0 : 1;
  float creg[4];                        // persistent c-state (4 units x row lm)
  const v4f vz = {0.f, 0.f, 0.f, 0.f};

#pragma unroll 1
  for (int t = 0; t < TT; ++t) {
    const int buf = t & 3;
    v4f PA[4] = {vz, vz, vz, vz}, PB[4] = {vz, vz, vz, vz};
    u64 g1v[4];

    if (L == 0) {
      // issue G1 loads early; consumed after the F1 round (latency hidden)
#pragma unroll
      for (int ct = 0; ct < 4; ++ct)
        g1v[ct] = g_G1[(((size_t)t * 32 + (w * 4 + ct)) * BB + row) * 4 + lq];
      if (t > 0) {
        v8s bh[4];
#pragma unroll
        for (int ks = 0; ks < 4; ++ks)
          bh[ks] = *reinterpret_cast<const v8s*>(
              reinterpret_cast<const char*>(s_h) + hswz(lm, ks * 64 + lq * 16));
#pragma unroll
        for (int ct = 0; ct < 4; ++ct)
#pragma unroll
          for (int ks = 0; ks < 4; ++ks)
            PA[ct] = __builtin_amdgcn_mfma_f32_16x16x32_bf16(afA[ct][ks], bh[ks], PA[ct], 0, 0, 0);
      }
    } else {
      // wait for h0[t] from the L0 block owning the same rows (usually instant)
      if (tid == 0) {
        while (aload(&g_F5[rb]) < base + t + 1) __builtin_amdgcn_s_sleep(1);
      }
      __syncthreads();
      __threadfence();
      const ush* hp = reinterpret_cast<const ush*>(g_h0s) + ((size_t)t * BB + row) * HH + lq * 8;
      v8s bh0[4];
#pragma unroll
      for (int ks = 0; ks < 4; ++ks) bh0[ks] = ld8(hp + ks * 32);   // 4 KB p2p
      if (t > 0) {                       // hh-GEMM first: hides the h0 load latency
        v8s bh1[4];
#pragma unroll
        for (int ks = 0; ks < 4; ++ks)
          bh1[ks] = *reinterpret_cast<const v8s*>(
              reinterpret_cast<const char*>(s_h) + hswz(lm, ks * 64 + lq * 16));
#pragma unroll
        for (int ct = 0; ct < 4; ++ct)
#pragma unroll
          for (int ks = 0; ks < 4; ++ks)
            PB[ct] = __builtin_amdgcn_mfma_f32_16x16x32_bf16(afB[ct][ks], bh1[ks], PB[ct], 0, 0, 0);
      }
#pragma unroll
      for (int ct = 0; ct < 4; ++ct)
#pragma unroll
        for (int ks = 0; ks < 4; ++ks)
          PA[ct] = __builtin_amdgcn_mfma_f32_16x16x32_bf16(afA[ct][ks], bh0[ks], PA[ct], 0, 0, 0);
    }

    // ---- gate stats: 16-row partials -> device atomics ----
#pragma unroll
    for (int ct = 0; ct < 4; ++ct) {
      const int m0 = (w * 4 + ct) * 16 + lq * 4;
#pragma unroll
      for (int r = 0; r < 4; ++r) {
        float s1 = PA[ct][r], q1 = s1 * s1;
        float s2 = PB[ct][r], q2 = s2 * s2;
#pragma unroll
        for (int off = 1; off < 16; off <<= 1) {
          s1 += __shfl_xor(s1, off); q1 += __shfl_xor(q1, off);
          if (L == 1) { s2 += __shfl_xor(s2, off); q2 += __shfl_xor(q2, off); }
        }
        if (lm == 0) {
          fadd(&g_acc[stA][buf][m0 + r][0], s1);
          fadd(&g_acc[stA][buf][m0 + r][1], q1);
          if (L == 1) {
            fadd(&g_acc[2][buf][m0 + r][0], s2);
            fadd(&g_acc[2][buf][m0 + r][1], q2);
          }
        }
      }
    }
    // signal + wait (round 1 of 2)
    __syncthreads();                     // drains all waves' atomics (vmcnt)
    if (tid == 0) { __threadfence(); astore(&g_F1[L][rb], base + t + 1); }
    if (tid < 64) {
      while (aload(&g_F1[L][tid]) < base + t + 1) __builtin_amdgcn_s_sleep(1);
    }
    __syncthreads();
    __threadfence();                     // acquire: invalidate stale L2 before sum reads

    // zero gate-accumulator slice for step t+2 (safe: <=1-step skew via F1 round)
    {
      const int zb = (t + 2) & 3;
      if (L == 0) {
        if (tid < 16) fzero(&g_acc[0][zb][rb * 8 + (tid >> 1)][tid & 1]);
      } else if (tid < 32) {
        const int st = 1 + (tid >> 4), k = tid & 15;
        fzero(&g_acc[st][zb][rb * 8 + (k >> 1)][k & 1]);
      }
    }

    // ---- coefs + pointwise + c update ----
    const bool first = (t == 0);
    float so_[4];
#pragma unroll
    for (int ct = 0; ct < 4; ++ct) {
      const int m0 = (w * 4 + ct) * 16 + lq * 4;
      const v4f ga  = *reinterpret_cast<const v4f*>(&s_gamA[m0]);
      const v4f bs  = *reinterpret_cast<const v4f*>(&s_bsum[m0]);
      const v4f sq0 = *reinterpret_cast<const v4f*>(&g_acc[stA][buf][m0][0]);
      const v4f sq1 = *reinterpret_cast<const v4f*>(&g_acc[stA][buf][m0 + 2][0]);
      float gv[4];
#pragma unroll
      for (int r = 0; r < 4; ++r) {
        const float S = (r < 2) ? sq0[r * 2] : sq1[(r - 2) * 2];
        const float Q = (r < 2) ? sq0[r * 2 + 1] : sq1[(r - 2) * 2 + 1];
        const float mu = S * (1.f / BB);
        const float var = Q * (1.f / BB) - mu * mu;
        const float A = ga[r] * rsqrtf(var + EPSB);
        gv[r] = A * (PA[ct][r] - mu) + bs[r];
      }
      if (L == 0) {
        const u64 g1 = g1v[ct];
        gv[0] += bf2f((ush)g1);         gv[1] += bf2f((ush)(g1 >> 16));
        gv[2] += bf2f((ush)(g1 >> 32)); gv[3] += bf2f((ush)(g1 >> 48));
      } else {
        const v4f gb = *reinterpret_cast<const v4f*>(&s_gamB[m0]);
        const v4f u0 = *reinterpret_cast<const v4f*>(&g_acc[2][buf][m0][0]);
        const v4f u1 = *reinterpret_cast<const v4f*>(&g_acc[2][buf][m0 + 2][0]);
#pragma unroll
        for (int r = 0; r < 4; ++r) {
          const float S = (r < 2) ? u0[r * 2] : u1[(r - 2) * 2];
          const float Q = (r < 2) ? u0[r * 2 + 1] : u1[(r - 2) * 2 + 1];
          const float mu = S * (1.f / BB);
          const float var = Q * (1.f / BB) - mu * mu;
          const float A = gb[r] * rsqrtf(var + EPSB);
          gv[r] += A * (PB[ct][r] - mu);
        }
      }
      const float cold = first ? 0.f : creg[ct];
      const float c1 = sigf(gv[0]) * cold + sigf(gv[1]) * tanhf_(gv[3]);
      creg[ct] = c1; so_[ct] = sigf(gv[2]);
      // c stats
      float cs = c1, cq = c1 * c1;
#pragma unroll
      for (int off = 1; off < 16; off <<= 1) { cs += __shfl_xor(cs, off); cq += __shfl_xor(cq, off); }
      if (lm == 0) {
        const int u = w * 16 + ct * 4 + lq;
        fadd(&g_cacc[L][buf][u][0], cs);
        fadd(&g_cacc[L][buf][u][1], cq);
      }
    }

    // signal + wait (round 2 of 2)
    __syncthreads();
    if (tid == 0) { __threadfence(); astore(&g_F3[L][rb], base + t + 1); }
    if (tid < 64) {
      while (aload(&g_F3[L][tid]) < base + t + 1) __builtin_amdgcn_s_sleep(1);
    }
    __syncthreads();
    __threadfence();

    if (tid < 4) fzero(&g_cacc[L][(t + 2) & 3][rb * 2 + (tid >> 1)][tid & 1]);

    // ---- c-BN + h output ----
#pragma unroll
    for (int ct = 0; ct < 4; ++ct) {
      const int u = w * 16 + ct * 4 + lq;
      const float S = g_cacc[L][buf][u][0], Q = g_cacc[L][buf][u][1];
      const float mu = S * (1.f / BB), var = Q * (1.f / BB) - mu * mu;
      const float ac = s_cg[u] * rsqrtf(var + EPSB);
      const float dc = s_cb[u] - ac * mu;
      const float h = so_[ct] * tanhf_(ac * creg[ct] + dc);
      const u32 v = (u32)f2bf(h);
      const u32 a = v | (__shfl_xor(v, 16) << 16);
      const u32 b2 = __shfl_xor(a, 32);
      if (lq == 0) {
        const u64 hv = (u64)a | ((u64)b2 << 32);
        *reinterpret_cast<u64*>(reinterpret_cast<char*>(s_h) + hswz(lm, (w * 4 + ct) * 8)) = hv;
        if (L == 0) g_h0s[((size_t)t * BB + row) * 32 + (w * 4 + ct)] = hv;
        else if (t == TT - 1) g_h1s[(size_t)row * 32 + (w * 4 + ct)] = hv;
      }
    }

    __syncthreads();                     // s_h visible for next iter; drains h stores
    if (L == 0 && tid == 0) { __threadfence(); astore(&g_F5[rb], base + t + 1); }
  }

  // ---- end-of-launch barrier, then restore accumulators (graph-replay safety) ----
  __syncthreads();
  if (tid == 0) { __threadfence(); astore(&g_Fend[bid], baseE + 1); }
  if (tid < 128) {
    while (aload(&g_Fend[tid]) < baseE + 1) __builtin_amdgcn_s_sleep(1);
  }
  __syncthreads();
  __threadfence();
#pragma unroll
  for (int zb = 2; zb < 4; ++zb) {       // bufs with adds after their last in-loop zero
    if (L == 0) {
      if (tid < 16) fzero(&g_acc[0][zb][rb * 8 + (tid >> 1)][tid & 1]);
    } else if (tid < 32) {
      const int st = 1 + (tid >> 4), k = tid & 15;
      fzero(&g_acc[st][zb][rb * 8 + (k >> 1)][k & 1]);
    }
    if (tid < 4) fzero(&g_cacc[L][zb][rb * 2 + (tid >> 1)][tid & 1]);
  }
}

// ---- epilogue: emb = h1(T-1) @ fc_w + fc_b (bf16 out) ----
__global__ __launch_bounds__(256) void kfc(const float* __restrict__ fcb) {
  const int tid = threadIdx.x, w = tid >> 6, l = tid & 63;
  const int lm = l & 15, lq = l >> 4;
  const int col = blockIdx.x * 16 + lm;   // grid 16
  const ush* hsrc = reinterpret_cast<const ush*>(g_h1s);
  v8s bf[4];
#pragma unroll
  for (int ks = 0; ks < 4; ++ks) bf[ks] = ld8(&g_fcwt[col * HH + ks * 32 + lq * 8]);
  const float bias = fcb[col];
  const v4f vz = {0.f, 0.f, 0.f, 0.f};
#pragma unroll
  for (int mt = 0; mt < 16; ++mt) {
    const int rowa = w * 256 + mt * 16 + lm;
    const ush* ap = hsrc + (size_t)rowa * HH + lq * 8;
    v4f acc = vz;
#pragma unroll
    for (int ks = 0; ks < 4; ++ks)
      acc = __builtin_amdgcn_mfma_f32_16x16x32_bf16(ld8(ap + ks * 32), bf[ks], acc, 0, 0, 0);
#pragma unroll
    for (int r = 0; r < 4; ++r) {
      int row = w * 256 + mt * 16 + lq * 4 + r;
      g_emb[row * OUTN + col] = f2bf(acc[r] + bias);
    }
  }
}

// ---- epilogue: out = emb @ dec_w + dec_b, transposed MFMA -> 16B coalesced stores ----
__global__ __launch_bounds__(256) void kdec(const float* __restrict__ decb, float* __restrict__ out) {
  const int tid = threadIdx.x, wv = tid >> 6, l = tid & 63;
  const int lm = l & 15, lq = l >> 4;
  const int c0 = blockIdx.x * 16;         // grid 600
  const int R0 = wv * 256;
  v8s af[8];
#pragma unroll
  for (int ks = 0; ks < 8; ++ks) af[ks] = ld8(&g_decwt[(size_t)(c0 + lm) * OUTN + ks * 32 + lq * 8]);
  float bias[4];
#pragma unroll
  for (int r = 0; r < 4; ++r) bias[r] = decb[c0 + lq * 4 + r];
  const v4f vz = {0.f, 0.f, 0.f, 0.f};
#pragma unroll
  for (int mt = 0; mt < 16; ++mt) {
    const int row = R0 + mt * 16 + lm;
    const ush* bp = g_emb + (size_t)row * OUTN + lq * 8;
    v4f acc = vz;
#pragma unroll
    for (int ks = 0; ks < 8; ++ks)
      acc = __builtin_amdgcn_mfma_f32_16x16x32_bf16(af[ks], ld8(bp + ks * 32), acc, 0, 0, 0);
    v4f o;
#pragma unroll
    for (int r = 0; r < 4; ++r) o[r] = acc[r] + bias[r];
    *reinterpret_cast<v4f*>(&out[(size_t)row * DECN + c0 + lq * 4]) = o;
  }
}

extern "C" void kernel_launch(void* const* d_in, const int* in_sizes, int n_in,
                              void* d_out, int out_size, void* d_ws, size_t ws_size,
                              hipStream_t stream) {
  const float* seq  = (const float*)d_in[0];
  const float* Wih0 = (const float*)d_in[1];
  const float* Whh0 = (const float*)d_in[2];
  const float* b0   = (const float*)d_in[3];
  const float* gih0 = (const float*)d_in[4];
  const float* bih0 = (const float*)d_in[5];
  const float* ghh0 = (const float*)d_in[6];
  const float* bhh0 = (const float*)d_in[7];
  const float* gc0  = (const float*)d_in[8];
  const float* bc0  = (const float*)d_in[9];
  const float* Wih1 = (const float*)d_in[10];
  const float* Whh1 = (const float*)d_in[11];
  const float* b1   = (const float*)d_in[12];
  const float* gih1 = (const float*)d_in[13];
  const float* bih1 = (const float*)d_in[14];
  const float* ghh1 = (const float*)d_in[15];
  const float* bhh1 = (const float*)d_in[16];
  const float* gc1  = (const float*)d_in[17];
  const float* bc1  = (const float*)d_in[18];
  const float* fcw  = (const float*)d_in[19];
  const float* fcb  = (const float*)d_in[20];
  const float* decw = (const float*)d_in[21];
  const float* decb = (const float*)d_in[22];
  float* out = (float*)d_out;
  (void)in_sizes; (void)n_in; (void)out_size; (void)d_ws; (void)ws_size;

  kpackx<<<dim3((TT * BB * KXP) / 256), dim3(256), 0, stream>>>(seq);
  kpackw<<<dim3(10688), dim3(256), 0, stream>>>(Wih0, Whh0, Wih1, Whh1, fcw, decw);
  kprep<<<dim3(TT * 8), dim3(512), 0, stream>>>(gih0, bih0, b0);
  krec2<<<dim3(128), dim3(512), 0, stream>>>(ghh0, bhh0, gc0, bc0,
                                             gih1, bih1, ghh1, bhh1, b1, gc1, bc1);
  kfc<<<dim3(16), dim3(256), 0, stream>>>(fcb);
  kdec<<<dim3(600), dim3(256), 0, stream>>>(decb, out);
}